// Round 2
// baseline (96.519 us; speedup 1.0000x reference)
//
#include <hip/hip_runtime.h>

// ViT block with "quantum" VQC layers on MI355X. FLOAT32 I/O (reference is
// jnp.float32; round-1 NaN came from misreading f32 inputs as bf16 — low
// halves of f32 mantissas decode as inf-bf16 with P=1/256).
//
// Key insight: the 8-qubit VQC (RX data layer + RX weight layer + CNOT ring)
// reduces exactly to prefix products of cos(x_i + W_i):
//   z_0 = prod_{i=1..7} cos(th_i),  z_k = prod_{i=0..k} cos(th_i)  (k>=1)
// because the pre-CNOT state is a product state (classical product
// distribution over basis states) and CNOTs only permute basis states;
// final bit k is the parity of original bits 0..k (bit 0 -> parity of 1..7),
// and expectations of parities of independent bits factorize.

#define SEQ 256
#define EMB 8

static __device__ __forceinline__ void load8f(const float* __restrict__ p, float v[8]) {
    float4 a = *reinterpret_cast<const float4*>(p);
    float4 b = *reinterpret_cast<const float4*>(p + 4);
    v[0] = a.x; v[1] = a.y; v[2] = a.z; v[3] = a.w;
    v[4] = b.x; v[5] = b.y; v[6] = b.z; v[7] = b.w;
}

static __device__ __forceinline__ void store8f(float* __restrict__ p, const float v[8]) {
    *reinterpret_cast<float4*>(p)     = make_float4(v[0], v[1], v[2], v[3]);
    *reinterpret_cast<float4*>(p + 4) = make_float4(v[4], v[5], v[6], v[7]);
}

// Closed-form 8-qubit VQC (see header comment).
static __device__ __forceinline__ void vqc8(const float in[8], const float W[8], float z[8]) {
    float c[8];
#pragma unroll
    for (int i = 0; i < 8; ++i) c[i] = __cosf(in[i] + W[i]);
    float t = c[1];
#pragma unroll
    for (int i = 2; i < 8; ++i) t *= c[i];
    z[0] = t;
    float acc = c[0];
#pragma unroll
    for (int i = 1; i < 8; ++i) { acc *= c[i]; z[i] = acc; }
}

static __device__ __forceinline__ void ln8(const float r[8], const float g[8], const float be[8], float o[8]) {
    float m = 0.f;
#pragma unroll
    for (int i = 0; i < 8; ++i) m += r[i];
    m *= 0.125f;
    float var = 0.f;
#pragma unroll
    for (int i = 0; i < 8; ++i) { float d = r[i] - m; var += d * d; }
    var *= 0.125f;
    float inv = rsqrtf(var + 1e-5f);
#pragma unroll
    for (int i = 0; i < 8; ++i) o[i] = (r[i] - m) * inv * g[i] + be[i];
}

__global__ __launch_bounds__(512) void vitq_kernel(
    const float* __restrict__ x,
    const float* __restrict__ Wq, const float* __restrict__ Wk,
    const float* __restrict__ Wv, const float* __restrict__ Wc,
    const float* __restrict__ Wf,
    const float* __restrict__ w1, const float* __restrict__ b1,
    const float* __restrict__ w2, const float* __restrict__ b2,
    const float* __restrict__ g1, const float* __restrict__ be1,
    const float* __restrict__ g2, const float* __restrict__ be2,
    float* __restrict__ out)
{
    __shared__ float Ks[SEQ][EMB];   // 8 KB
    __shared__ float Vs[SEQ][EMB];   // 8 KB
    __shared__ float Cs[SEQ][EMB];   // 8 KB (ctx)

    const int b   = blockIdx.x;
    const int tid = threadIdx.x;
    const int s   = tid & (SEQ - 1);
    const int h   = tid >> 8;        // 0 or 1 (wave-uniform)

    // ---- per-token input ----
    float xv[8];
    load8f(x + ((size_t)(b * SEQ + s)) * EMB, xv);

    // ---- Q/K/V via closed-form VQC ----
    float wrow[8], q[8];
    load8f(Wq, wrow);
    vqc8(xv, wrow, q);
    if (h == 0) {
        float k[8];
        load8f(Wk, wrow);
        vqc8(xv, wrow, k);
#pragma unroll
        for (int i = 0; i < 8; ++i) Ks[s][i] = k[i];
    } else {
        float v[8];
        load8f(Wv, wrow);
        vqc8(xv, wrow, v);
#pragma unroll
        for (int i = 0; i < 8; ++i) Vs[s][i] = v[i];
    }
    __syncthreads();

    // ---- attention, head h. Scores bounded: |q_i|,|k_i|<=1 -> |q.k|<=4,
    // *0.5 -> |sc|<=2, so plain exp-sum is safe (sum < 256*e^2). ----
    const int ho = 4 * h;
    float qh[4];
#pragma unroll
    for (int d = 0; d < 4; ++d) qh[d] = q[ho + d] * 0.5f;   // fold 1/sqrt(dk)

    float l = 0.f;
    float acc0 = 0.f, acc1 = 0.f, acc2 = 0.f, acc3 = 0.f;
#pragma unroll 8
    for (int kk = 0; kk < SEQ; ++kk) {
        float4 kr = *reinterpret_cast<const float4*>(&Ks[kk][ho]);  // broadcast read
        float4 vr = *reinterpret_cast<const float4*>(&Vs[kk][ho]);
        float sc = qh[0] * kr.x + qh[1] * kr.y + qh[2] * kr.z + qh[3] * kr.w;
        float e  = __expf(sc);
        l    += e;
        acc0 += e * vr.x;
        acc1 += e * vr.y;
        acc2 += e * vr.z;
        acc3 += e * vr.w;
    }
    float inv = 1.f / l;
    Cs[s][ho + 0] = acc0 * inv;
    Cs[s][ho + 1] = acc1 * inv;
    Cs[s][ho + 2] = acc2 * inv;
    Cs[s][ho + 3] = acc3 * inv;
    __syncthreads();

    // ---- tail: vqc(Wc), LN1, FFN with vqc(Wf), LN2 (h==0 half-block only) ----
    if (h == 0) {
        float ctx[8];
#pragma unroll
        for (int i = 0; i < 8; ++i) ctx[i] = Cs[s][i];

        float ao[8];
        load8f(Wc, wrow);
        vqc8(ctx, wrow, ao);

        float r[8];
#pragma unroll
        for (int i = 0; i < 8; ++i) r[i] = xv[i] + ao[i];

        float g[8], be[8], x1[8];
        load8f(g1, g); load8f(be1, be);
        ln8(r, g, be, x1);

        // h = x1 @ w1.T + b1
        float wf[64], bias[8];
#pragma unroll
        for (int i = 0; i < 64; ++i) wf[i] = w1[i];
        load8f(b1, bias);
        float hv[8];
#pragma unroll
        for (int j = 0; j < 8; ++j) {
            float a = bias[j];
#pragma unroll
            for (int i = 0; i < 8; ++i) a += x1[i] * wf[j * 8 + i];
            hv[j] = a;
        }

        float hq[8];
        load8f(Wf, wrow);
        vqc8(hv, wrow, hq);

        // ff = hq @ w2.T + b2
#pragma unroll
        for (int i = 0; i < 64; ++i) wf[i] = w2[i];
        load8f(b2, bias);
        float r2[8];
#pragma unroll
        for (int j = 0; j < 8; ++j) {
            float a = bias[j];
#pragma unroll
            for (int i = 0; i < 8; ++i) a += hq[i] * wf[j * 8 + i];
            r2[j] = x1[j] + a;
        }

        float o[8];
        load8f(g2, g); load8f(be2, be);
        ln8(r2, g, be, o);

        store8f(out + ((size_t)(b * SEQ + s)) * EMB, o);
    }
}

extern "C" void kernel_launch(void* const* d_in, const int* in_sizes, int n_in,
                              void* d_out, int out_size, void* d_ws, size_t ws_size,
                              hipStream_t stream) {
    const float* x   = (const float*)d_in[0];
    const float* Wq  = (const float*)d_in[1];
    const float* Wk  = (const float*)d_in[2];
    const float* Wv  = (const float*)d_in[3];
    const float* Wc  = (const float*)d_in[4];
    const float* Wf  = (const float*)d_in[5];
    const float* w1  = (const float*)d_in[6];
    const float* b1  = (const float*)d_in[7];
    const float* w2  = (const float*)d_in[8];
    const float* b2  = (const float*)d_in[9];
    const float* g1  = (const float*)d_in[10];
    const float* be1 = (const float*)d_in[11];
    const float* g2  = (const float*)d_in[12];
    const float* be2 = (const float*)d_in[13];
    float* out = (float*)d_out;

    const int B = in_sizes[0] / (SEQ * EMB);   // 64
    vitq_kernel<<<B, 512, 0, stream>>>(x, Wq, Wk, Wv, Wc, Wf, w1, b1, w2, b2,
                                       g1, be1, g2, be2, out);
}

// Round 3
// 86.927 us; speedup vs baseline: 1.1103x; 1.1103x over previous
//
#include <hip/hip_runtime.h>

// ViT block with "quantum" VQC layers on MI355X — float32 I/O.
//
// VQC closed form: the 8-qubit circuit (RX data layer + RX weight layer +
// CNOT ring) reduces exactly to prefix products of cos(x_i + W_i):
//   z_0 = prod_{i=1..7} cos(th_i),  z_k = prod_{i=0..k} cos(th_i)  (k>=1)
// (product state -> CNOT ring is a basis permutation -> bit k becomes parity
// of bits 0..k; expectations of parities of independent bits factorize).
//
// R3 structure: grid = B*4 blocks (256 total, one per CU). Each block owns
// 64 query tokens; 512 threads = 128 (token,head) pairs x 4 key-splits of 64
// keys each. Scores are bounded (|q.k|*0.5 <= 2) so plain exp-sum is exact-
// safe and split partials combine by addition in LDS.

#define SEQ 256
#define EMB 8
#define QG  64    // query tokens per block
#define NSPLIT 4  // key splits

static __device__ __forceinline__ void load8f(const float* __restrict__ p, float v[8]) {
    float4 a = *reinterpret_cast<const float4*>(p);
    float4 b = *reinterpret_cast<const float4*>(p + 4);
    v[0] = a.x; v[1] = a.y; v[2] = a.z; v[3] = a.w;
    v[4] = b.x; v[5] = b.y; v[6] = b.z; v[7] = b.w;
}

static __device__ __forceinline__ void store8f(float* __restrict__ p, const float v[8]) {
    *reinterpret_cast<float4*>(p)     = make_float4(v[0], v[1], v[2], v[3]);
    *reinterpret_cast<float4*>(p + 4) = make_float4(v[4], v[5], v[6], v[7]);
}

// Closed-form 8-qubit VQC (see header comment).
static __device__ __forceinline__ void vqc8(const float in[8], const float W[8], float z[8]) {
    float c[8];
#pragma unroll
    for (int i = 0; i < 8; ++i) c[i] = __cosf(in[i] + W[i]);
    float t = c[1];
#pragma unroll
    for (int i = 2; i < 8; ++i) t *= c[i];
    z[0] = t;
    float acc = c[0];
#pragma unroll
    for (int i = 1; i < 8; ++i) { acc *= c[i]; z[i] = acc; }
}

static __device__ __forceinline__ void ln8(const float r[8], const float g[8], const float be[8], float o[8]) {
    float m = 0.f;
#pragma unroll
    for (int i = 0; i < 8; ++i) m += r[i];
    m *= 0.125f;
    float var = 0.f;
#pragma unroll
    for (int i = 0; i < 8; ++i) { float d = r[i] - m; var += d * d; }
    var *= 0.125f;
    float inv = rsqrtf(var + 1e-5f);
#pragma unroll
    for (int i = 0; i < 8; ++i) o[i] = (r[i] - m) * inv * g[i] + be[i];
}

__global__ __launch_bounds__(512) void vitq_kernel(
    const float* __restrict__ x,
    const float* __restrict__ Wq, const float* __restrict__ Wk,
    const float* __restrict__ Wv, const float* __restrict__ Wc,
    const float* __restrict__ Wf,
    const float* __restrict__ w1, const float* __restrict__ b1,
    const float* __restrict__ w2, const float* __restrict__ b2,
    const float* __restrict__ g1, const float* __restrict__ be1,
    const float* __restrict__ g2, const float* __restrict__ be2,
    float* __restrict__ out)
{
    __shared__ float Ks[SEQ][EMB];                 // 8 KB
    __shared__ float Vs[SEQ][EMB];                 // 8 KB
    __shared__ float P[NSPLIT][2 * QG][5];         // 10 KB partials (stride 5 -> 2-way = free)

    const int bi  = blockIdx.x;
    const int b   = bi >> 2;          // batch
    const int g   = bi & 3;           // query group (64 tokens)
    const int tid = threadIdx.x;
    const int p   = tid & 127;        // (token,head) pair
    const int j   = tid >> 7;         // key split 0..3   (wave-uniform)
    const int sl  = p & 63;           // local token
    const int h   = p >> 6;           // head             (wave-uniform)
    const int s   = g * QG + sl;      // global token in batch

    const float* xb = x + ((size_t)b * SEQ) * EMB;

    // ---- Q for my (token,head); keep xq for the residual/tail ----
    float xq[8], wrow[8], q[8];
    load8f(xb + (size_t)s * EMB, xq);
    load8f(Wq, wrow);
    vqc8(xq, wrow, q);

    // ---- stage K/V for all 256 tokens of batch b ----
    {
        const int t = tid & 255;
        float xs[8], kv[8];
        load8f(xb + (size_t)t * EMB, xs);
        if (tid < 256) {
            load8f(Wk, wrow);
            vqc8(xs, wrow, kv);
            store8f(&Ks[t][0], kv);
        } else {
            load8f(Wv, wrow);
            vqc8(xs, wrow, kv);
            store8f(&Vs[t][0], kv);
        }
    }
    __syncthreads();

    // ---- attention partial over my 64-key slice (plain exp-sum: |sc|<=2) ----
    const int ho = 4 * h;
    float qh[4];
#pragma unroll
    for (int d = 0; d < 4; ++d) qh[d] = q[ho + d] * 0.5f;   // fold 1/sqrt(dk)

    float l = 0.f, acc0 = 0.f, acc1 = 0.f, acc2 = 0.f, acc3 = 0.f;
    const int k0 = j * 64;
#pragma unroll 8
    for (int kk = k0; kk < k0 + 64; ++kk) {
        float4 kr = *reinterpret_cast<const float4*>(&Ks[kk][ho]);  // broadcast
        float4 vr = *reinterpret_cast<const float4*>(&Vs[kk][ho]);
        float sc = qh[0] * kr.x + qh[1] * kr.y + qh[2] * kr.z + qh[3] * kr.w;
        float e  = __expf(sc);
        l    += e;
        acc0 += e * vr.x;
        acc1 += e * vr.y;
        acc2 += e * vr.z;
        acc3 += e * vr.w;
    }
    P[j][p][0] = l;
    P[j][p][1] = acc0;
    P[j][p][2] = acc1;
    P[j][p][3] = acc2;
    P[j][p][4] = acc3;
    __syncthreads();

    // ---- reduce splits + tail, one thread per owned token ----
    if (tid < QG) {
        float ctx[8];
#pragma unroll
        for (int hh = 0; hh < 2; ++hh) {
            const int pp = hh * QG + tid;
            float ll = 0.f, a0 = 0.f, a1 = 0.f, a2 = 0.f, a3 = 0.f;
#pragma unroll
            for (int jj = 0; jj < NSPLIT; ++jj) {
                ll += P[jj][pp][0];
                a0 += P[jj][pp][1];
                a1 += P[jj][pp][2];
                a2 += P[jj][pp][3];
                a3 += P[jj][pp][4];
            }
            float inv = 1.f / ll;
            ctx[4 * hh + 0] = a0 * inv;
            ctx[4 * hh + 1] = a1 * inv;
            ctx[4 * hh + 2] = a2 * inv;
            ctx[4 * hh + 3] = a3 * inv;
        }

        float ao[8];
        load8f(Wc, wrow);
        vqc8(ctx, wrow, ao);

        float r[8];
#pragma unroll
        for (int i = 0; i < 8; ++i) r[i] = xq[i] + ao[i];   // xq: this thread is (j=0,h=0,sl=tid)

        float gg[8], be[8], x1[8];
        load8f(g1, gg); load8f(be1, be);
        ln8(r, gg, be, x1);

        // hv = x1 @ w1.T + b1
        float wf[64], bias[8];
#pragma unroll
        for (int i = 0; i < 64; ++i) wf[i] = w1[i];
        load8f(b1, bias);
        float hv[8];
#pragma unroll
        for (int jj = 0; jj < 8; ++jj) {
            float a = bias[jj];
#pragma unroll
            for (int i = 0; i < 8; ++i) a += x1[i] * wf[jj * 8 + i];
            hv[jj] = a;
        }

        float hq[8];
        load8f(Wf, wrow);
        vqc8(hv, wrow, hq);

        // ff = hq @ w2.T + b2 ; residual ; LN2
#pragma unroll
        for (int i = 0; i < 64; ++i) wf[i] = w2[i];
        load8f(b2, bias);
        float r2[8];
#pragma unroll
        for (int jj = 0; jj < 8; ++jj) {
            float a = bias[jj];
#pragma unroll
            for (int i = 0; i < 8; ++i) a += hq[i] * wf[jj * 8 + i];
            r2[jj] = x1[jj] + a;
        }

        float o[8];
        load8f(g2, gg); load8f(be2, be);
        ln8(r2, gg, be, o);

        store8f(out + ((size_t)(b * SEQ + s)) * EMB, o);
    }
}

extern "C" void kernel_launch(void* const* d_in, const int* in_sizes, int n_in,
                              void* d_out, int out_size, void* d_ws, size_t ws_size,
                              hipStream_t stream) {
    const float* x   = (const float*)d_in[0];
    const float* Wq  = (const float*)d_in[1];
    const float* Wk  = (const float*)d_in[2];
    const float* Wv  = (const float*)d_in[3];
    const float* Wc  = (const float*)d_in[4];
    const float* Wf  = (const float*)d_in[5];
    const float* w1  = (const float*)d_in[6];
    const float* b1  = (const float*)d_in[7];
    const float* w2  = (const float*)d_in[8];
    const float* b2  = (const float*)d_in[9];
    const float* g1  = (const float*)d_in[10];
    const float* be1 = (const float*)d_in[11];
    const float* g2  = (const float*)d_in[12];
    const float* be2 = (const float*)d_in[13];
    float* out = (float*)d_out;

    const int B = in_sizes[0] / (SEQ * EMB);   // 64
    vitq_kernel<<<B * 4, 512, 0, stream>>>(x, Wq, Wk, Wv, Wc, Wf, w1, b1, w2, b2,
                                           g1, be1, g2, be2, out);
}